// Round 9
// baseline (132.016 us; speedup 1.0000x reference)
//
#include <hip/hip_runtime.h>
#include <hip/hip_bf16.h>

#define TEMP_INV 14.285714285714286f  // 1/0.07
#define FSCALE 16.0f                  // fp8 pre-scale per operand
#define T1S (TEMP_INV / 256.0f)       // acc = 256*sim -> (sim-1)/T = acc*T1S - TEMP_INV
#define NSLICE 16

typedef __attribute__((ext_vector_type(4))) float f32x4;
typedef __attribute__((ext_vector_type(4))) int i32x4;
typedef __attribute__((ext_vector_type(8))) int i32x8;

// ---- fq FRAGMENT-MAJOR layout ----
// 2KB tiles: tile(rg, kb), rg = row/16, kb = kbyte/128. Fragment (lane) =
// lo16B at tile+lane*16, hi16B at tile+1024+lane*16 -> two lane-consecutive
// 1KB global loads per fragment.

// ---- row L2-normalize -> fp8 e4m3 (x16) into fragment-major layout ----
__global__ __launch_bounds__(256) void norm_k(const float* __restrict__ feat,
                                              uchar* __restrict__ fq,
                                              const int* __restrict__ labels,
                                              const int* __restrict__ kptr,
                                              int* __restrict__ glab,
                                              float* __restrict__ gacc,
                                              int* __restrict__ dcnt,
                                              int N, int D) {
  const int row = (blockIdx.x * 256 + threadIdx.x) >> 6;
  const int lane = threadIdx.x & 63;
  if (row < N) {
    const float4* fr = (const float4*)(feat + (size_t)row * D);
    float4 v0 = fr[lane * 2];
    float4 v1 = fr[lane * 2 + 1];
    float ss = v0.x * v0.x + v0.y * v0.y + v0.z * v0.z + v0.w * v0.w +
               v1.x * v1.x + v1.y * v1.y + v1.z * v1.z + v1.w * v1.w;
    #pragma unroll
    for (int off = 32; off; off >>= 1) ss += __shfl_xor(ss, off, 64);
    const float inv = FSCALE / fmaxf(sqrtf(ss), 1e-12f);
    int w0 = 0, w1 = 0;
    w0 = __builtin_amdgcn_cvt_pk_fp8_f32(v0.x * inv, v0.y * inv, w0, false);
    w0 = __builtin_amdgcn_cvt_pk_fp8_f32(v0.z * inv, v0.w * inv, w0, true);
    w1 = __builtin_amdgcn_cvt_pk_fp8_f32(v1.x * inv, v1.y * inv, w1, false);
    w1 = __builtin_amdgcn_cvt_pk_fp8_f32(v1.z * inv, v1.w * inv, w1, true);
    uint2 o; o.x = (uint)w0; o.y = (uint)w1;
    const int tkb  = lane >> 4;
    const int quad = (lane >> 2) & 3;
    const int half = (lane >> 1) & 1;
    const int slot = half * 64 + quad * 16 + (row & 15);
    uchar* dstp = fq + (((size_t)(row >> 4) * (D >> 7) + tkb) << 11) +
                  slot * 16 + (lane & 1) * 8;
    *(uint2*)dstp = o;
    if (lane == 0) {
      const int k = *kptr;
      glab[row] = labels[(size_t)(row / k) * k];
    }
  }
  if (blockIdx.x == 0 && threadIdx.x < 3) {
    if (threadIdx.x < 2) gacc[threadIdx.x] = 0.f;
    else *dcnt = 0;
  }
}

// ---- flash-style fused GEMM + online masked-softmax stats ----
// r22: r21 with 16 column-slices (512 cols, 8 j-steps/wave) -> 4096 waves =
// exactly 4 waves/SIMD at VGPR ~112 (r21 supplied only 2/SIMD; occupancy was
// grid-limited). Otherwise identical to r21.
__global__ __launch_bounds__(128) void gemm_k(const uchar* __restrict__ fq,
                                              const int* __restrict__ glab,
                                              float* __restrict__ partS,
                                              float* __restrict__ partP,
                                              int N, int D) {
  const int lane = threadIdx.x & 63;
  const int wid  = threadIdx.x >> 6;
  const int quad = lane >> 4, l15 = lane & 15;
  const int ktiles = D >> 7;
  const int strip = (int)(blockIdx.x / NSLICE) * 2 + wid;
  const int slice = (int)(blockIdx.x % NSLICE);
  const int r0 = strip * 32;
  const int cps = N / NSLICE;             // 512
  const int jsteps = cps >> 6;            // 8
  const int j0base = slice * cps;

  int rlab[2][4];
  #pragma unroll
  for (int mi = 0; mi < 2; mi++)
    #pragma unroll
    for (int r = 0; r < 4; r++)
      rlab[mi][r] = glab[r0 + mi * 16 + quad * 4 + r];

  float Srun[2][4] = {{0.f, 0.f, 0.f, 0.f}, {0.f, 0.f, 0.f, 0.f}};
  float Prun[2][4] = {{0.f, 0.f, 0.f, 0.f}, {0.f, 0.f, 0.f, 0.f}};

#define LOADF(dst, grp, kt)                                                   \
  {                                                                           \
    const uchar* p_ = fq + (((size_t)((grp) * ktiles + (kt))) << 11) + lane * 16; \
    i32x4 lo_ = *(const i32x4*)p_;                                            \
    i32x4 hi_ = *(const i32x4*)(p_ + 1024);                                   \
    dst = (i32x8){lo_.x, lo_.y, lo_.z, lo_.w, hi_.x, hi_.y, hi_.z, hi_.w};    \
  }

#define EPILOG(j0)                                                            \
  {                                                                           \
    int clab[4];                                                              \
    _Pragma("unroll")                                                         \
    for (int ni = 0; ni < 4; ni++) clab[ni] = glab[(j0) + ni * 16 + l15];     \
    _Pragma("unroll")                                                         \
    for (int mi = 0; mi < 2; mi++)                                            \
      _Pragma("unroll")                                                       \
      for (int r = 0; r < 4; r++) {                                           \
        const int row = r0 + mi * 16 + quad * 4 + r;                          \
        const int rl = rlab[mi][r];                                           \
        float s = 0.f, pp = 0.f;                                              \
        _Pragma("unroll")                                                     \
        for (int ni = 0; ni < 4; ni++) {                                      \
          const int col = (j0) + ni * 16 + l15;                               \
          const float lg = fmaf(acc[mi][ni][r], T1S, -TEMP_INV);              \
          const bool diag = (col == row);                                     \
          s += diag ? 0.f : __expf(lg);                                       \
          pp += (!diag && rl == clab[ni]) ? lg : 0.f;                         \
        }                                                                     \
        Srun[mi][r] += s;                                                     \
        Prun[mi][r] += pp;                                                    \
      }                                                                       \
  }

  if (ktiles == 4) {
    i32x8 af[2][4];
    #pragma unroll
    for (int mi = 0; mi < 2; mi++)
      #pragma unroll
      for (int kt = 0; kt < 4; kt++)
        LOADF(af[mi][kt], (r0 >> 4) + mi, kt)

    for (int js = 0; js < jsteps; js++) {
      const int j0 = j0base + js * 64;
      f32x4 acc[2][4];
      #pragma unroll
      for (int mi = 0; mi < 2; mi++)
        #pragma unroll
        for (int ni = 0; ni < 4; ni++) {
          f32x4 z = {0.f, 0.f, 0.f, 0.f};
          acc[mi][ni] = z;
        }
      #pragma unroll
      for (int kt = 0; kt < 4; kt++) {
        i32x8 bv[4];
        #pragma unroll
        for (int ni = 0; ni < 4; ni++)
          LOADF(bv[ni], (j0 >> 4) + ni, kt)
        #pragma unroll
        for (int mi = 0; mi < 2; mi++)
          #pragma unroll
          for (int ni = 0; ni < 4; ni++)
            acc[mi][ni] = __builtin_amdgcn_mfma_scale_f32_16x16x128_f8f6f4(
                af[mi][kt], bv[ni], acc[mi][ni], 0, 0, 0, 127, 0, 127);
      }
      EPILOG(j0)
    }
  } else {
    for (int js = 0; js < jsteps; js++) {
      const int j0 = j0base + js * 64;
      f32x4 acc[2][4];
      #pragma unroll
      for (int mi = 0; mi < 2; mi++)
        #pragma unroll
        for (int ni = 0; ni < 4; ni++) {
          f32x4 z = {0.f, 0.f, 0.f, 0.f};
          acc[mi][ni] = z;
        }
      for (int kt = 0; kt < ktiles; kt++) {
        i32x8 as[2], bv[4];
        #pragma unroll
        for (int mi = 0; mi < 2; mi++) LOADF(as[mi], (r0 >> 4) + mi, kt)
        #pragma unroll
        for (int ni = 0; ni < 4; ni++) LOADF(bv[ni], (j0 >> 4) + ni, kt)
        #pragma unroll
        for (int mi = 0; mi < 2; mi++)
          #pragma unroll
          for (int ni = 0; ni < 4; ni++)
            acc[mi][ni] = __builtin_amdgcn_mfma_scale_f32_16x16x128_f8f6f4(
                as[mi], bv[ni], acc[mi][ni], 0, 0, 0, 127, 0, 127);
      }
      EPILOG(j0)
    }
  }
#undef LOADF
#undef EPILOG

  #pragma unroll
  for (int mi = 0; mi < 2; mi++)
    #pragma unroll
    for (int r = 0; r < 4; r++) {
      float s = Srun[mi][r], p = Prun[mi][r];
      #pragma unroll
      for (int off = 1; off < 16; off <<= 1) {
        s += __shfl_xor(s, off, 64);
        p += __shfl_xor(p, off, 64);
      }
      if (l15 == 0) {
        const int row = r0 + mi * 16 + quad * 4 + r;
        partS[(size_t)row * NSLICE + slice] = s;
        partP[(size_t)row * NSLICE + slice] = p;
      }
    }
}

// ---- per-row slice-sum + histogram -> loss ----
__global__ __launch_bounds__(256) void reduce_loss_k(const float* __restrict__ partS,
                                                     const float* __restrict__ partP,
                                                     const int* __restrict__ glab,
                                                     const int* __restrict__ labels,
                                                     const int* __restrict__ kptr,
                                                     float* __restrict__ gacc,
                                                     int* __restrict__ dcnt,
                                                     float* __restrict__ out, int N) {
  const int tt = threadIdx.x;
  const int row = blockIdx.x * 256 + tt;
  const int k = *kptr;
  const int B = N / k;

  __shared__ int h[64];
  if (tt < 64) h[tt] = 0;
  __syncthreads();
  for (int g = tt; g < B; g += 256) {
    int lb = labels[(size_t)g * k];
    if (lb >= 0 && lb < 64) atomicAdd(&h[lb], 1);
  }
  __syncthreads();

  float l = 0.f, v = 0.f;
  if (row < N) {
    float S = 0.f, P = 0.f;
    #pragma unroll
    for (int s = 0; s < NSLICE; s++) {
      S += partS[(size_t)row * NSLICE + s];
      P += partP[(size_t)row * NSLICE + s];
    }
    const int np = h[glab[row]] * k - 1;
    if (np > 0) {
      l = -(P - (float)np * logf(S + 1e-8f)) / (float)np;
      v = 1.f;
    }
  }
  #pragma unroll
  for (int off = 32; off; off >>= 1) {
    l += __shfl_xor(l, off, 64);
    v += __shfl_xor(v, off, 64);
  }
  __shared__ float sl4[4], sv4[4];
  if ((tt & 63) == 0) { sl4[tt >> 6] = l; sv4[tt >> 6] = v; }
  __syncthreads();
  if (tt == 0) {
    float L = 0.f, V = 0.f;
    #pragma unroll
    for (int i = 0; i < 4; i++) { L += sl4[i]; V += sv4[i]; }
    atomicAdd(&gacc[0], L);
    atomicAdd(&gacc[1], V);
    __threadfence();
    const int prev = atomicAdd(dcnt, 1);
    if (prev == (int)gridDim.x - 1) {
      const float Lf = atomicAdd(&gacc[0], 0.f);
      const float Vf = atomicAdd(&gacc[1], 0.f);
      out[0] = Lf / fmaxf(Vf, 1.f);
    }
  }
}

extern "C" void kernel_launch(void* const* d_in, const int* in_sizes, int n_in,
                              void* d_out, int out_size, void* d_ws, size_t ws_size,
                              hipStream_t stream) {
  const float* feat = (const float*)d_in[0];
  const int* labels = (const int*)d_in[1];
  const int* kptr   = (const int*)d_in[2];
  const int N = in_sizes[1];
  const int D = in_sizes[0] / N;  // 512

  char* ws = (char*)d_ws;
  uchar* fq = (uchar*)ws;
  size_t off = (size_t)N * D;
  float* partS = (float*)(ws + off); off += (size_t)N * NSLICE * sizeof(float);
  float* partP = (float*)(ws + off); off += (size_t)N * NSLICE * sizeof(float);
  int* glab    = (int*)(ws + off);   off += (size_t)N * sizeof(int);
  float* gacc  = (float*)(ws + off); off += 2 * sizeof(float);
  int* dcnt    = (int*)(ws + off);   off += sizeof(int);

  const int strips = N / 32;                 // 256
  const int ggrid = (strips / 2) * NSLICE;   // 2048 blocks x 128 threads

  norm_k<<<(N + 3) / 4, 256, 0, stream>>>(feat, fq, labels, kptr, glab,
                                          gacc, dcnt, N, D);
  gemm_k<<<ggrid, 128, 0, stream>>>(fq, glab, partS, partP, N, D);
  reduce_loss_k<<<(N + 255) / 256, 256, 0, stream>>>(partS, partP, glab, labels,
                                                     kptr, gacc, dcnt,
                                                     (float*)d_out, N);
}

// Round 10
// 127.405 us; speedup vs baseline: 1.0362x; 1.0362x over previous
//
#include <hip/hip_runtime.h>
#include <hip/hip_bf16.h>

#define TEMP_INV 14.285714285714286f  // 1/0.07
#define FSCALE 16.0f                  // fp8 pre-scale per operand
#define T1S (TEMP_INV / 256.0f)       // acc = 256*sim -> (sim-1)/T = acc*T1S - TEMP_INV
#define INV_LN2 1.4426950408889634f
#define LN2F 0.6931471805599453f
#define T1S2 (T1S * INV_LN2)          // log2-domain slope
#define TI2  (TEMP_INV * INV_LN2)     // log2-domain offset

typedef __attribute__((ext_vector_type(4))) float f32x4;
typedef __attribute__((ext_vector_type(4))) int i32x4;
typedef __attribute__((ext_vector_type(8))) int i32x8;

// ---- fq FRAGMENT-MAJOR layout ----
// 2KB tiles: tile(rg, kb), rg = row/16, kb = kbyte/128. Fragment (lane) =
// lo16B at tile+lane*16, hi16B at tile+1024+lane*16 -> two lane-consecutive
// 1KB global loads per fragment.

// ---- row L2-normalize -> fp8 e4m3 (x16) into fragment-major layout ----
__global__ __launch_bounds__(256) void norm_k(const float* __restrict__ feat,
                                              uchar* __restrict__ fq,
                                              const int* __restrict__ labels,
                                              const int* __restrict__ kptr,
                                              int* __restrict__ glab,
                                              float* __restrict__ gacc,
                                              int* __restrict__ dcnt,
                                              int N, int D) {
  const int row = (blockIdx.x * 256 + threadIdx.x) >> 6;
  const int lane = threadIdx.x & 63;
  if (row < N) {
    const float4* fr = (const float4*)(feat + (size_t)row * D);
    float4 v0 = fr[lane * 2];
    float4 v1 = fr[lane * 2 + 1];
    float ss = v0.x * v0.x + v0.y * v0.y + v0.z * v0.z + v0.w * v0.w +
               v1.x * v1.x + v1.y * v1.y + v1.z * v1.z + v1.w * v1.w;
    #pragma unroll
    for (int off = 32; off; off >>= 1) ss += __shfl_xor(ss, off, 64);
    const float inv = FSCALE / fmaxf(sqrtf(ss), 1e-12f);
    int w0 = 0, w1 = 0;
    w0 = __builtin_amdgcn_cvt_pk_fp8_f32(v0.x * inv, v0.y * inv, w0, false);
    w0 = __builtin_amdgcn_cvt_pk_fp8_f32(v0.z * inv, v0.w * inv, w0, true);
    w1 = __builtin_amdgcn_cvt_pk_fp8_f32(v1.x * inv, v1.y * inv, w1, false);
    w1 = __builtin_amdgcn_cvt_pk_fp8_f32(v1.z * inv, v1.w * inv, w1, true);
    uint2 o; o.x = (uint)w0; o.y = (uint)w1;
    const int tkb  = lane >> 4;
    const int quad = (lane >> 2) & 3;
    const int half = (lane >> 1) & 1;
    const int slot = half * 64 + quad * 16 + (row & 15);
    uchar* dstp = fq + (((size_t)(row >> 4) * (D >> 7) + tkb) << 11) +
                  slot * 16 + (lane & 1) * 8;
    *(uint2*)dstp = o;
    if (lane == 0) {
      const int k = *kptr;
      glab[row] = labels[(size_t)(row / k) * k];
    }
  }
  if (blockIdx.x == 0 && threadIdx.x < 3) {
    if (threadIdx.x < 2) gacc[threadIdx.x] = 0.f;
    else *dcnt = 0;
  }
}

// ---- flash-style fused GEMM + online masked-softmax stats ----
// r23 = r21 (best measured: 125.7us) + epilogue VALU cuts:
//  (1) diag-hoisting: the strip's diagonal falls in exactly ONE j-step of
//      one slice (scalar diagJ); 15/16 j-steps use EPILOG_FAST with no
//      col/diag logic.
//  (2) exp2-direct: lg2 in log2 units, S += exp2f(lg2) (v_exp_f32 IS exp2,
//      drops the ln2 mul per element), P accumulated in log2 units and
//      scaled by ln2 once per strip at store.
// Geometry identical to r21: wave = 32-row strip x 1024-col slice (16
// j-steps), A-fragments register-cached once, slice = blockIdx&7.
__global__ __launch_bounds__(128) void gemm_k(const uchar* __restrict__ fq,
                                              const int* __restrict__ glab,
                                              float* __restrict__ partS,
                                              float* __restrict__ partP,
                                              int N, int D) {
  const int lane = threadIdx.x & 63;
  const int wid  = threadIdx.x >> 6;
  const int quad = lane >> 4, l15 = lane & 15;
  const int ktiles = D >> 7;              // 4 at D=512
  const int strip = (blockIdx.x >> 3) * 2 + wid;   // 0..N/32-1
  const int slice = blockIdx.x & 7;                // XCD-pinned col slice
  const int r0 = strip * 32;
  const int cps = N >> 3;                 // cols per slice (1024)
  const int jsteps = cps >> 6;            // 16
  const int j0base = slice * cps;

  // the single j-step of this slice that can contain diagonal elements
  int diagJ = -1;
  if (r0 >= j0base && r0 < j0base + cps) diagJ = (r0 - j0base) >> 6;

  int rlab[2][4];
  #pragma unroll
  for (int mi = 0; mi < 2; mi++)
    #pragma unroll
    for (int r = 0; r < 4; r++)
      rlab[mi][r] = glab[r0 + mi * 16 + quad * 4 + r];

  float Srun[2][4] = {{0.f, 0.f, 0.f, 0.f}, {0.f, 0.f, 0.f, 0.f}};
  float Prun[2][4] = {{0.f, 0.f, 0.f, 0.f}, {0.f, 0.f, 0.f, 0.f}};  // log2 units

#define LOADF(dst, grp, kt)                                                   \
  {                                                                           \
    const uchar* p_ = fq + (((size_t)((grp) * ktiles + (kt))) << 11) + lane * 16; \
    i32x4 lo_ = *(const i32x4*)p_;                                            \
    i32x4 hi_ = *(const i32x4*)(p_ + 1024);                                   \
    dst = (i32x8){lo_.x, lo_.y, lo_.z, lo_.w, hi_.x, hi_.y, hi_.z, hi_.w};    \
  }

#define EPILOG_FAST(j0)                                                       \
  {                                                                           \
    int clab[4];                                                              \
    _Pragma("unroll")                                                         \
    for (int ni = 0; ni < 4; ni++) clab[ni] = glab[(j0) + ni * 16 + l15];     \
    _Pragma("unroll")                                                         \
    for (int mi = 0; mi < 2; mi++)                                            \
      _Pragma("unroll")                                                       \
      for (int r = 0; r < 4; r++) {                                           \
        const int rl = rlab[mi][r];                                           \
        float s = 0.f, pp = 0.f;                                              \
        _Pragma("unroll")                                                     \
        for (int ni = 0; ni < 4; ni++) {                                      \
          const float lg2 = fmaf(acc[mi][ni][r], T1S2, -TI2);                 \
          s += exp2f(lg2);                                                    \
          pp += (rl == clab[ni]) ? lg2 : 0.f;                                 \
        }                                                                     \
        Srun[mi][r] += s;                                                     \
        Prun[mi][r] += pp;                                                    \
      }                                                                       \
  }

#define EPILOG_DIAG(j0)                                                       \
  {                                                                           \
    int clab[4];                                                              \
    _Pragma("unroll")                                                         \
    for (int ni = 0; ni < 4; ni++) clab[ni] = glab[(j0) + ni * 16 + l15];     \
    _Pragma("unroll")                                                         \
    for (int mi = 0; mi < 2; mi++)                                            \
      _Pragma("unroll")                                                       \
      for (int r = 0; r < 4; r++) {                                           \
        const int row = r0 + mi * 16 + quad * 4 + r;                          \
        const int rl = rlab[mi][r];                                           \
        float s = 0.f, pp = 0.f;                                              \
        _Pragma("unroll")                                                     \
        for (int ni = 0; ni < 4; ni++) {                                      \
          const int col = (j0) + ni * 16 + l15;                               \
          const float lg2 = fmaf(acc[mi][ni][r], T1S2, -TI2);                 \
          const bool diag = (col == row);                                     \
          s += diag ? 0.f : exp2f(lg2);                                       \
          pp += (!diag && rl == clab[ni]) ? lg2 : 0.f;                        \
        }                                                                     \
        Srun[mi][r] += s;                                                     \
        Prun[mi][r] += pp;                                                    \
      }                                                                       \
  }

  if (ktiles == 4) {
    i32x8 af[2][4];
    #pragma unroll
    for (int mi = 0; mi < 2; mi++)
      #pragma unroll
      for (int kt = 0; kt < 4; kt++)
        LOADF(af[mi][kt], (r0 >> 4) + mi, kt)

    for (int js = 0; js < jsteps; js++) {
      const int j0 = j0base + js * 64;
      f32x4 acc[2][4];
      #pragma unroll
      for (int mi = 0; mi < 2; mi++)
        #pragma unroll
        for (int ni = 0; ni < 4; ni++) {
          f32x4 z = {0.f, 0.f, 0.f, 0.f};
          acc[mi][ni] = z;
        }
      #pragma unroll
      for (int kt = 0; kt < 4; kt++) {
        i32x8 bv[4];
        #pragma unroll
        for (int ni = 0; ni < 4; ni++)
          LOADF(bv[ni], (j0 >> 4) + ni, kt)
        #pragma unroll
        for (int mi = 0; mi < 2; mi++)
          #pragma unroll
          for (int ni = 0; ni < 4; ni++)
            acc[mi][ni] = __builtin_amdgcn_mfma_scale_f32_16x16x128_f8f6f4(
                af[mi][kt], bv[ni], acc[mi][ni], 0, 0, 0, 127, 0, 127);
      }
      if (js == diagJ) { EPILOG_DIAG(j0) } else { EPILOG_FAST(j0) }
    }
  } else {
    for (int js = 0; js < jsteps; js++) {
      const int j0 = j0base + js * 64;
      f32x4 acc[2][4];
      #pragma unroll
      for (int mi = 0; mi < 2; mi++)
        #pragma unroll
        for (int ni = 0; ni < 4; ni++) {
          f32x4 z = {0.f, 0.f, 0.f, 0.f};
          acc[mi][ni] = z;
        }
      for (int kt = 0; kt < ktiles; kt++) {
        i32x8 as[2], bv[4];
        #pragma unroll
        for (int mi = 0; mi < 2; mi++) LOADF(as[mi], (r0 >> 4) + mi, kt)
        #pragma unroll
        for (int ni = 0; ni < 4; ni++) LOADF(bv[ni], (j0 >> 4) + ni, kt)
        #pragma unroll
        for (int mi = 0; mi < 2; mi++)
          #pragma unroll
          for (int ni = 0; ni < 4; ni++)
            acc[mi][ni] = __builtin_amdgcn_mfma_scale_f32_16x16x128_f8f6f4(
                as[mi], bv[ni], acc[mi][ni], 0, 0, 0, 127, 0, 127);
      }
      if (js == diagJ) { EPILOG_DIAG(j0) } else { EPILOG_FAST(j0) }
    }
  }
#undef LOADF
#undef EPILOG_FAST
#undef EPILOG_DIAG

  // one shuffle-reduce per strip; P scaled back to natural-log units here
  #pragma unroll
  for (int mi = 0; mi < 2; mi++)
    #pragma unroll
    for (int r = 0; r < 4; r++) {
      float s = Srun[mi][r], p = Prun[mi][r];
      #pragma unroll
      for (int off = 1; off < 16; off <<= 1) {
        s += __shfl_xor(s, off, 64);
        p += __shfl_xor(p, off, 64);
      }
      if (l15 == 0) {
        const int row = r0 + mi * 16 + quad * 4 + r;
        partS[(size_t)row * 8 + slice] = s;
        partP[(size_t)row * 8 + slice] = p * LN2F;
      }
    }
}

// ---- per-row slice-sum + histogram -> loss ----
__global__ __launch_bounds__(256) void reduce_loss_k(const float* __restrict__ partS,
                                                     const float* __restrict__ partP,
                                                     const int* __restrict__ glab,
                                                     const int* __restrict__ labels,
                                                     const int* __restrict__ kptr,
                                                     float* __restrict__ gacc,
                                                     int* __restrict__ dcnt,
                                                     float* __restrict__ out, int N) {
  const int tt = threadIdx.x;
  const int row = blockIdx.x * 256 + tt;
  const int k = *kptr;
  const int B = N / k;

  __shared__ int h[64];
  if (tt < 64) h[tt] = 0;
  __syncthreads();
  for (int g = tt; g < B; g += 256) {
    int lb = labels[(size_t)g * k];
    if (lb >= 0 && lb < 64) atomicAdd(&h[lb], 1);
  }
  __syncthreads();

  float l = 0.f, v = 0.f;
  if (row < N) {
    float S = 0.f, P = 0.f;
    #pragma unroll
    for (int s = 0; s < 8; s++) {
      S += partS[(size_t)row * 8 + s];
      P += partP[(size_t)row * 8 + s];
    }
    const int np = h[glab[row]] * k - 1;
    if (np > 0) {
      l = -(P - (float)np * logf(S + 1e-8f)) / (float)np;
      v = 1.f;
    }
  }
  #pragma unroll
  for (int off = 32; off; off >>= 1) {
    l += __shfl_xor(l, off, 64);
    v += __shfl_xor(v, off, 64);
  }
  __shared__ float sl4[4], sv4[4];
  if ((tt & 63) == 0) { sl4[tt >> 6] = l; sv4[tt >> 6] = v; }
  __syncthreads();
  if (tt == 0) {
    float L = 0.f, V = 0.f;
    #pragma unroll
    for (int i = 0; i < 4; i++) { L += sl4[i]; V += sv4[i]; }
    atomicAdd(&gacc[0], L);
    atomicAdd(&gacc[1], V);
    __threadfence();
    const int prev = atomicAdd(dcnt, 1);
    if (prev == (int)gridDim.x - 1) {
      const float Lf = atomicAdd(&gacc[0], 0.f);
      const float Vf = atomicAdd(&gacc[1], 0.f);
      out[0] = Lf / fmaxf(Vf, 1.f);
    }
  }
}

extern "C" void kernel_launch(void* const* d_in, const int* in_sizes, int n_in,
                              void* d_out, int out_size, void* d_ws, size_t ws_size,
                              hipStream_t stream) {
  const float* feat = (const float*)d_in[0];
  const int* labels = (const int*)d_in[1];
  const int* kptr   = (const int*)d_in[2];
  const int N = in_sizes[1];
  const int D = in_sizes[0] / N;  // 512

  char* ws = (char*)d_ws;
  uchar* fq = (uchar*)ws;
  size_t off = (size_t)N * D;  // fp8: 1 byte/elem
  float* partS = (float*)(ws + off); off += (size_t)N * 8 * sizeof(float);
  float* partP = (float*)(ws + off); off += (size_t)N * 8 * sizeof(float);
  int* glab    = (int*)(ws + off);   off += (size_t)N * sizeof(int);
  float* gacc  = (float*)(ws + off); off += 2 * sizeof(float);
  int* dcnt    = (int*)(ws + off);   off += sizeof(int);

  const int strips = N / 32;            // 256
  const int ggrid = (strips / 2) * 8;   // 1024 blocks x 128 threads

  norm_k<<<(N + 3) / 4, 256, 0, stream>>>(feat, fq, labels, kptr, glab,
                                          gacc, dcnt, N, D);
  gemm_k<<<ggrid, 128, 0, stream>>>(fq, glab, partS, partP, N, D);
  reduce_loss_k<<<(N + 255) / 256, 256, 0, stream>>>(partS, partP, glab, labels,
                                                     kptr, gacc, dcnt,
                                                     (float*)d_out, N);
}